// Round 2
// baseline (677.373 us; speedup 1.0000x reference)
//
#include <hip/hip_runtime.h>
#include <cstdint>
#include <math.h>

// Problem constants: B=32, TXT_T=256, MEL_T=1600, N_MEL=40
#define BB   32
#define LLEN 256
#define TLEN 1600
#define NC   40
#define NEGPADF (-1.0e12f)
#define NEGPADD (-1.0e12)

// Output layout (floats): mdn_loss[32] | alignment[32*1600*256] | lp[32*256*1600]
#define OFF_ALIGN 32
#define OFF_LP    (32 + (size_t)BB * TLEN * LLEN)

// Workspace layout (bytes):
//   Ad   : double[32*256*80]   = 5,242,880 B
//   Kcd  : double[32*256]      =    65,536 B
//   lpTh : float[32*1600*256]  = 52,428,800 B
//   path : int[32*1600]        =   204,800 B        total ~57.9 MB
#define WSB_A    0
#define WSB_KC   (WSB_A + (size_t)BB * LLEN * 80 * 8)
#define WSB_LPT  (WSB_KC + (size_t)BB * LLEN * 8)
#define WSB_PATH (WSB_LPT + (size_t)BB * TLEN * LLEN * 4)

__device__ __forceinline__ int imin(int a, int b) { return a < b ? a : b; }

// Raw workgroup barrier waiting LDS ops only (lgkmcnt(0)), NOT vmcnt, so the
// global prefetch ring stays in flight across DP steps.
__device__ __forceinline__ void sync_lds() {
  asm volatile("" ::: "memory");
  __builtin_amdgcn_s_waitcnt(0xC07F);   // vmcnt=63, expcnt=7, lgkmcnt=0
  __builtin_amdgcn_s_barrier();
  asm volatile("" ::: "memory");
}

// ---------------------------------------------------------------------------
// K0 (f64): a1[c] = -0.5/C*invvar, a2[c] = (1/C)*mu*invvar,
//           Kc = -0.5/C*(sum mu^2*invvar + sum logvar)
// ---------------------------------------------------------------------------
__global__ __launch_bounds__(256) void prep_kernel(
    const float* __restrict__ mu_logvar, double* __restrict__ A, double* __restrict__ Kc) {
  int row = blockIdx.x * 4 + (threadIdx.x >> 6);   // b*256 + l
  int lane = threadIdx.x & 63;
  const float* src = mu_logvar + (size_t)row * (2 * NC);
  double mu = 0.0, lv = 0.0, iv = 0.0, part = 0.0;
  if (lane < NC) {
    mu = (double)src[lane];
    lv = (double)src[NC + lane];
    iv = exp(-lv);
    part = mu * mu * iv + lv;
  }
  for (int m = 1; m < 64; m <<= 1) part += __shfl_xor(part, m, 64);
  const double s = -0.5 / (double)NC;
  if (lane < NC) {
    A[(size_t)row * 80 + lane]      = s * iv;
    A[(size_t)row * 80 + NC + lane] = (1.0 / (double)NC) * mu * iv;
  }
  if (lane == 0) Kc[row] = s * part;
}

// ---------------------------------------------------------------------------
// K1 (f64): lp[b][l][t] = Kc + sum_c (a1*z^2 + a2*z), computed in f64.
// Writes: lp output (f32), lpT hi (f32, ws), lpT lo (f32, stashed in the
// alignment output region as scratch — zeroed later by zero_kernel).
// ---------------------------------------------------------------------------
__global__ __launch_bounds__(256) void lp_kernel(
    const float* __restrict__ z, const double* __restrict__ A,
    const double* __restrict__ Kc, float* __restrict__ out,
    float* __restrict__ lpTh) {
  int b = blockIdx.y;
  int t0 = blockIdx.x * 256;
  int tid = threadIdx.x;
  int t = t0 + tid;
  int tv = imin(t, TLEN - 1);
  bool act = (t < TLEN);

  float* lp_out = out + OFF_LP;
  float* loS    = out + OFF_ALIGN;   // lo scratch, layout [b][t][l]

  float zr[NC];
  const float* zb = z + (size_t)b * NC * TLEN;
  #pragma unroll
  for (int c = 0; c < NC; ++c) zr[c] = zb[(size_t)c * TLEN + tv];

  __shared__ __align__(16) double tile[256][33];
  const double* Ab = A + (size_t)b * LLEN * 80;
  const double* Kb = Kc + (size_t)b * LLEN;

  for (int chunk = 0; chunk < 8; ++chunk) {
    for (int j = 0; j < 32; ++j) {
      int l = chunk * 32 + j;
      const double* Ar = Ab + (size_t)l * 80;    // wave-uniform -> s_load
      double a0 = Kb[l], a1 = 0.0, a2 = 0.0, a3 = 0.0;
      #pragma unroll
      for (int c = 0; c < NC; c += 2) {
        double z0 = (double)zr[c], z1 = (double)zr[c + 1];
        a0 = fma(Ar[c],          z0 * z0, a0);
        a1 = fma(Ar[NC + c],     z0,      a1);
        a2 = fma(Ar[c + 1],      z1 * z1, a2);
        a3 = fma(Ar[NC + c + 1], z1,      a3);
      }
      double accd = (a0 + a2) + (a1 + a3);
      if (act) lp_out[((size_t)b * LLEN + l) * TLEN + t] = (float)accd;
      tile[tid][j] = accd;
    }
    __syncthreads();
    #pragma unroll
    for (int p = 0; p < 8; ++p) {
      int idx = p * 256 + tid;
      int r = idx >> 3;          // t-row 0..255
      int c4 = idx & 7;          // float4 col within 32
      int tr = t0 + r;
      if (tr < TLEN) {
        float h[4], lo[4];
        #pragma unroll
        for (int i = 0; i < 4; ++i) {
          double d = tile[r][c4 * 4 + i];
          float hh = (float)d;
          h[i] = hh;
          lo[i] = (float)(d - (double)hh);
        }
        size_t base = ((size_t)b * TLEN + tr) * LLEN + chunk * 32 + c4 * 4;
        *(float4*)(lpTh + base) = make_float4(h[0], h[1], h[2], h[3]);
        *(float4*)(loS + base)  = make_float4(lo[0], lo[1], lo[2], lo[3]);
      }
    }
    __syncthreads();
  }
}

// ---------------------------------------------------------------------------
// K2: blocks 0..31 = forward logsumexp (f32, unchanged — validated);
//     blocks 32..63 = Viterbi max-DP in f64 (hi+lo lp) + D-bits + literal
//     backtrack.
// ---------------------------------------------------------------------------
__global__ __launch_bounds__(256) void dp_kernel(
    const float* __restrict__ lpTh, const float* __restrict__ outR,
    const int* __restrict__ tlen, const int* __restrict__ mlen,
    float* __restrict__ out, int* __restrict__ pathg) {
  int bid = blockIdx.x;
  int tid = threadIdx.x;
  bool is_beta = (bid >= BB);
  int b = is_beta ? bid - BB : bid;
  int tl = tlen[b];
  int ml = mlen[b];
  const float* lpb = lpTh + (size_t)b * TLEN * LLEN;
  const float* lob = outR + OFF_ALIGN + (size_t)b * TLEN * LLEN;

  __shared__ __align__(16) float  xbuf[2][256];
  __shared__ __align__(16) double xbufd[2][256];
  __shared__ uint32_t Dbits[256][TLEN / 32];

  if (!is_beta) {
    // -------- forward logsumexp DP (f32) --------
    float lp00 = lpb[0];
    float ring[8];
    #pragma unroll
    for (int k = 0; k < 8; ++k)
      ring[k] = lpb[(size_t)imin(1 + k, TLEN - 1) * LLEN + tid];
    float v  = (tid == 0) ? lp00 : NEGPADF;
    float sh = (tid == 1) ? lp00 : NEGPADF;
    auto astep = [&](int t, float& slot) {
      float lpv = slot;
      slot = lpb[(size_t)imin(t + 8, TLEN - 1) * LLEN + tid];
      float a = v + 1e-7f, g = sh + 1e-7f;
      float m = fmaxf(a, g);
      float d = fabsf(a - g);
      float lg = __logf(1.0f + __expf(-d));
      v = m + lg + lpv;
      xbuf[t & 1][tid] = v;
      sync_lds();
      float shn = xbuf[t & 1][(tid + 255) & 255];
      sh = (tid == 0) ? NEGPADF : shn;
    };
    int t = 1;
    for (; t + 7 < ml; t += 8) {
      astep(t + 0, ring[0]); astep(t + 1, ring[1]);
      astep(t + 2, ring[2]); astep(t + 3, ring[3]);
      astep(t + 4, ring[4]); astep(t + 5, ring[5]);
      astep(t + 6, ring[6]); astep(t + 7, ring[7]);
    }
    #pragma unroll
    for (int k = 0; k < 8; ++k) { if (t + k < ml) astep(t + k, ring[k]); }
    if (tid == tl - 1) out[b] = -v / (float)ml;
  } else {
    // -------- Viterbi max-DP (f64) --------
    double lp00 = (double)lpb[0] + (double)lob[0];
    float ring_h[8], ring_l[8];
    #pragma unroll
    for (int k = 0; k < 8; ++k) {
      size_t idx = (size_t)imin(1 + k, TLEN - 1) * LLEN + tid;
      ring_h[k] = lpb[idx];
      ring_l[k] = lob[idx];
    }
    double v  = (tid == 0) ? lp00 : NEGPADD;
    double sh = (tid == 1) ? lp00 : NEGPADD;
    uint32_t acc = (tid == 1) ? 1u : 0u;   // D[1][0] = (beta0[0] > -PAD) = true
    auto bstep = [&](int t, float& sh_, float& sl_) {
      double lpv = (double)sh_ + (double)sl_;
      size_t nidx = (size_t)imin(t + 8, TLEN - 1) * LLEN + tid;
      sh_ = lpb[nidx];
      sl_ = lob[nidx];
      v = fmax(v, sh) + lpv;
      xbufd[t & 1][tid] = v;
      sync_lds();
      double shn = xbufd[t & 1][(tid + 255) & 255];
      if (shn > v) acc |= (1u << (t & 31));
      if ((t & 31) == 31) { Dbits[tid][t >> 5] = acc; acc = 0u; }
      sh = (tid == 0) ? NEGPADD : shn;
    };
    int t = 1;
    for (; t + 7 < ml; t += 8) {
      bstep(t + 0, ring_h[0], ring_l[0]); bstep(t + 1, ring_h[1], ring_l[1]);
      bstep(t + 2, ring_h[2], ring_l[2]); bstep(t + 3, ring_h[3], ring_l[3]);
      bstep(t + 4, ring_h[4], ring_l[4]); bstep(t + 5, ring_h[5], ring_l[5]);
      bstep(t + 6, ring_h[6], ring_l[6]); bstep(t + 7, ring_h[7], ring_l[7]);
    }
    #pragma unroll
    for (int k = 0; k < 8; ++k) { if (t + k < ml) bstep(t + k, ring_h[k], ring_l[k]); }
    if (((ml - 1) & 31) != 31) Dbits[tid][(ml - 1) >> 5] = acc;
    __syncthreads();

    // -------- literal backtrack (reference semantics, cached bit-word) -----
    if (tid == 0) {
      int* pb = pathg + b * TLEN;
      int r = tl - 1;
      pb[ml - 1] = r;
      int curR = 1 << 30, curW = -1;
      uint32_t W = 0;
      for (int q = ml - 2; q >= 0; --q) {
        int w = q >> 5;
        if (r >= 0 && (r != curR || w != curW)) { W = Dbits[r][w]; curR = r; curW = w; }
        int g = (r >= 0) ? (int)((W >> (q & 31)) & 1u) : 0;
        r -= g;                 // floor at -1 automatic: g==0 once r<0
        pb[q] = r;
      }
    }
  }
}

// ---------------------------------------------------------------------------
// K3: zero the alignment region (it held lo-scratch until now).
// ---------------------------------------------------------------------------
__global__ __launch_bounds__(256) void zero_kernel(float* __restrict__ out) {
  size_t i = ((size_t)blockIdx.x * 256 + threadIdx.x) * 4;
  *(float4*)(out + OFF_ALIGN + i) = make_float4(0.f, 0.f, 0.f, 0.f);
}

// ---------------------------------------------------------------------------
// K4: scatter the one-hot 1.0 entries.
// ---------------------------------------------------------------------------
__global__ __launch_bounds__(256) void ones_kernel(
    const int* __restrict__ mlen, const int* __restrict__ pathg, float* __restrict__ out) {
  int b = blockIdx.x;
  int ml = mlen[b];
  float* al = out + OFF_ALIGN;
  for (int t = threadIdx.x; t < ml; t += 256) {
    int p = pathg[b * TLEN + t];
    if (p >= 0) al[((size_t)b * TLEN + t) * LLEN + p] = 1.0f;
  }
}

extern "C" void kernel_launch(void* const* d_in, const int* in_sizes, int n_in,
                              void* d_out, int out_size, void* d_ws, size_t ws_size,
                              hipStream_t stream) {
  const float* mu_logvar = (const float*)d_in[0];
  const float* z         = (const float*)d_in[1];
  const int*   tlv       = (const int*)d_in[2];
  const int*   mlv       = (const int*)d_in[3];
  float* out = (float*)d_out;
  char*  wsb = (char*)d_ws;

  double* Ad   = (double*)(wsb + WSB_A);
  double* Kcd  = (double*)(wsb + WSB_KC);
  float*  lpTh = (float*)(wsb + WSB_LPT);
  int*    path = (int*)(wsb + WSB_PATH);

  prep_kernel<<<dim3(BB * LLEN / 4), 256, 0, stream>>>(mu_logvar, Ad, Kcd);
  lp_kernel<<<dim3(7, BB), 256, 0, stream>>>(z, Ad, Kcd, out, lpTh);
  dp_kernel<<<dim3(2 * BB), 256, 0, stream>>>(lpTh, out, tlv, mlv, out, path);
  zero_kernel<<<dim3((BB * TLEN * LLEN) / (256 * 4)), 256, 0, stream>>>(out);
  ones_kernel<<<dim3(BB), 256, 0, stream>>>(mlv, path, out);
}

// Round 3
// 588.827 us; speedup vs baseline: 1.1504x; 1.1504x over previous
//
#include <hip/hip_runtime.h>
#include <cstdint>
#include <math.h>

// Problem constants: B=32, TXT_T=256, MEL_T=1600, N_MEL=40
#define BB   32
#define LLEN 256
#define TLEN 1600
#define NC   40
#define NEGPADF (-1.0e12f)
#define NEGPADD (-1.0e12)

// Output layout (floats): mdn_loss[32] | alignment[32*1600*256] | lp[32*256*1600]
#define OFF_ALIGN 32
#define OFF_LP    (32 + (size_t)BB * TLEN * LLEN)

// Workspace layout (bytes): Ad double[32*256*80] | Kcd double[32*256] |
// lpTh float[32*1600*256] | path int[32*1600]   (~57.9 MB)
#define WSB_A    0
#define WSB_KC   (WSB_A + (size_t)BB * LLEN * 80 * 8)
#define WSB_LPT  (WSB_KC + (size_t)BB * LLEN * 8)
#define WSB_PATH (WSB_LPT + (size_t)BB * TLEN * LLEN * 4)

__device__ __forceinline__ int imin(int a, int b) { return a < b ? a : b; }

__device__ __forceinline__ float lsef(float a, float b) {
  a += 1e-7f; b += 1e-7f;
  float m = fmaxf(a, b);
  float d = fabsf(a - b);
  return m + __logf(1.0f + __expf(-d));
}

// ---------------------------------------------------------------------------
// K0 (f64): a1 = -0.5/C*invvar, a2 = (1/C)*mu*invvar, Kc = -0.5/C*(sum mu^2*iv + sum lv)
// ---------------------------------------------------------------------------
__global__ __launch_bounds__(256) void prep_kernel(
    const float* __restrict__ mu_logvar, double* __restrict__ A, double* __restrict__ Kc) {
  int row = blockIdx.x * 4 + (threadIdx.x >> 6);   // b*256 + l
  int lane = threadIdx.x & 63;
  const float* src = mu_logvar + (size_t)row * (2 * NC);
  double mu = 0.0, lv = 0.0, iv = 0.0, part = 0.0;
  if (lane < NC) {
    mu = (double)src[lane];
    lv = (double)src[NC + lane];
    iv = exp(-lv);
    part = mu * mu * iv + lv;
  }
  for (int m = 1; m < 64; m <<= 1) part += __shfl_xor(part, m, 64);
  const double s = -0.5 / (double)NC;
  if (lane < NC) {
    A[(size_t)row * 80 + lane]      = s * iv;
    A[(size_t)row * 80 + NC + lane] = (1.0 / (double)NC) * mu * iv;
  }
  if (lane == 0) Kc[row] = s * part;
}

// ---------------------------------------------------------------------------
// K1 (f64): lp[b][l][t] = Kc + sum_c (a1*z^2 + a2*z).  Grid (13, 8, 32),
// 128 threads: t-tile x l-chunk x batch for ~13 blocks/CU occupancy.
// Writes lp output (f32), lpT hi (ws), lpT lo (alignment region scratch).
// ---------------------------------------------------------------------------
__global__ __launch_bounds__(128) void lp_kernel(
    const float* __restrict__ z, const double* __restrict__ A,
    const double* __restrict__ Kc, float* __restrict__ out,
    float* __restrict__ lpTh) {
  int b  = blockIdx.z;
  int l0 = blockIdx.y * 32;
  int t0 = blockIdx.x * 128;
  int tid = threadIdx.x;
  int t = t0 + tid;
  int tv = imin(t, TLEN - 1);
  bool act = (t < TLEN);

  float* lp_out = out + OFF_LP;
  float* loS    = out + OFF_ALIGN;   // lo scratch [b][t][l], zeroed later

  float zr[NC];
  const float* zb = z + (size_t)b * NC * TLEN;
  #pragma unroll
  for (int c = 0; c < NC; ++c) zr[c] = zb[(size_t)c * TLEN + tv];

  __shared__ __align__(16) double tile[128][33];
  const double* Ab = A + ((size_t)b * LLEN + l0) * 80;
  const double* Kb = Kc + (size_t)b * LLEN + l0;

  #pragma unroll 2
  for (int j = 0; j < 32; ++j) {
    const double* Ar = Ab + (size_t)j * 80;      // wave-uniform -> s_load
    double a0 = Kb[j], a1 = 0.0, a2 = 0.0, a3 = 0.0;
    #pragma unroll
    for (int c = 0; c < NC; c += 2) {
      double z0 = (double)zr[c], z1 = (double)zr[c + 1];
      a0 = fma(Ar[c],          z0 * z0, a0);
      a1 = fma(Ar[NC + c],     z0,      a1);
      a2 = fma(Ar[c + 1],      z1 * z1, a2);
      a3 = fma(Ar[NC + c + 1], z1,      a3);
    }
    double accd = (a0 + a2) + (a1 + a3);
    if (act) lp_out[((size_t)b * LLEN + l0 + j) * TLEN + t] = (float)accd;
    tile[tid][j] = accd;
  }
  __syncthreads();
  #pragma unroll
  for (int p = 0; p < 8; ++p) {
    int idx = p * 128 + tid;
    int r = idx >> 3, c4 = idx & 7;
    int tr = t0 + r;
    if (tr < TLEN) {
      float h[4], lo[4];
      #pragma unroll
      for (int i = 0; i < 4; ++i) {
        double d = tile[r][c4 * 4 + i];
        float hh = (float)d;
        h[i] = hh;
        lo[i] = (float)(d - (double)hh);
      }
      size_t base = ((size_t)b * TLEN + tr) * LLEN + l0 + c4 * 4;
      *(float4*)(lpTh + base) = make_float4(h[0], h[1], h[2], h[3]);
      *(float4*)(loS + base)  = make_float4(lo[0], lo[1], lo[2], lo[3]);
    }
  }
}

// ---------------------------------------------------------------------------
// K2: one WAVE per chain, no barriers. Lane i owns rows 4i..4i+3; cross-row
// neighbor via one rotate-shuffle per step. Blocks 0..31 alpha (f32 lse),
// 32..63 beta (f64 Viterbi + decision bits + backtrack).
// ---------------------------------------------------------------------------
__global__ __launch_bounds__(64) void dp_kernel(
    const float* __restrict__ lpTh, const float* __restrict__ outR,
    const int* __restrict__ tlen, const int* __restrict__ mlen,
    float* __restrict__ out, int* __restrict__ pathg) {
  int bid = blockIdx.x;
  int lane = threadIdx.x;            // 0..63
  bool is_beta = (bid >= BB);
  int b = is_beta ? bid - BB : bid;
  int tl = tlen[b];
  int ml = mlen[b];
  const float* lpb = lpTh + (size_t)b * TLEN * LLEN;
  const float* lob = outR + OFF_ALIGN + (size_t)b * TLEN * LLEN;
  int rsrc = (lane + 63) & 63;       // rotate: lane i <- lane i-1 (lane0 <- 63)

  if (!is_beta) {
    // -------- forward logsumexp DP (f32) --------
    float4 ring[16];
    #pragma unroll
    for (int k = 0; k < 16; ++k)
      ring[k] = *(const float4*)(lpb + (size_t)imin(1 + k, TLEN - 1) * LLEN + 4 * lane);
    float lp00 = lpb[0];
    float o0 = (lane == 0) ? lp00 : NEGPADF;
    float o1 = NEGPADF, o2 = NEGPADF, o3 = NEGPADF;
    float q = __shfl(o3, rsrc, 64);
    auto step = [&](int t, float4& slot) {
      float4 lp4 = slot;
      slot = *(const float4*)(lpb + (size_t)imin(t + 16, TLEN - 1) * LLEN + 4 * lane);
      float p = (lane == 0) ? NEGPADF : q;
      float n0 = lsef(o0, p)  + lp4.x;
      float n1 = lsef(o1, o0) + lp4.y;
      float n2 = lsef(o2, o1) + lp4.z;
      float n3 = lsef(o3, o2) + lp4.w;
      o0 = n0; o1 = n1; o2 = n2; o3 = n3;
      q = __shfl(o3, rsrc, 64);
    };
    int t = 1;
    for (; t + 15 < ml; t += 16) {
      step(t + 0,  ring[0]);  step(t + 1,  ring[1]);
      step(t + 2,  ring[2]);  step(t + 3,  ring[3]);
      step(t + 4,  ring[4]);  step(t + 5,  ring[5]);
      step(t + 6,  ring[6]);  step(t + 7,  ring[7]);
      step(t + 8,  ring[8]);  step(t + 9,  ring[9]);
      step(t + 10, ring[10]); step(t + 11, ring[11]);
      step(t + 12, ring[12]); step(t + 13, ring[13]);
      step(t + 14, ring[14]); step(t + 15, ring[15]);
    }
    #pragma unroll
    for (int k = 0; k < 16; ++k) { if (t + k < ml) step(t + k, ring[k]); }
    int fr = tl - 1;
    if (lane == (fr >> 2)) {
      int s = fr & 3;
      float val = (s == 0) ? o0 : (s == 1) ? o1 : (s == 2) ? o2 : o3;
      out[b] = -val / (float)ml;
    }
  } else {
    // -------- Viterbi max-DP (f64) + decision bits --------
    __shared__ uint32_t Dbits[256][TLEN / 32];
    float4 rh[16], rl[16];
    #pragma unroll
    for (int k = 0; k < 16; ++k) {
      size_t off = (size_t)imin(1 + k, TLEN - 1) * LLEN + 4 * lane;
      rh[k] = *(const float4*)(lpb + off);
      rl[k] = *(const float4*)(lob + off);
    }
    double lp00 = (double)lpb[0] + (double)lob[0];
    double o0 = (lane == 0) ? lp00 : NEGPADD;
    double o1 = NEGPADD, o2 = NEGPADD, o3 = NEGPADD;
    double q = __shfl(o3, rsrc, 64);
    uint32_t a0 = 0, a1 = (lane == 0) ? 1u : 0u, a2 = 0, a3 = 0;  // t=0: row1 bit
    auto step = [&](int t, float4& sh, float4& sl) {
      double l0 = (double)sh.x + (double)sl.x;
      double l1 = (double)sh.y + (double)sl.y;
      double l2 = (double)sh.z + (double)sl.z;
      double l3 = (double)sh.w + (double)sl.w;
      size_t off = (size_t)imin(t + 16, TLEN - 1) * LLEN + 4 * lane;
      sh = *(const float4*)(lpb + off);
      sl = *(const float4*)(lob + off);
      double p = (lane == 0) ? NEGPADD : q;
      double n0 = fmax(o0, p)  + l0;
      double n1 = fmax(o1, o0) + l1;
      double n2 = fmax(o2, o1) + l2;
      double n3 = fmax(o3, o2) + l3;
      q = __shfl(n3, rsrc, 64);          // wrap value: row 4i-1 (mod 256) final beta
      uint32_t bit = 1u << (t & 31);
      if (q  > n0) a0 |= bit;
      if (n0 > n1) a1 |= bit;
      if (n1 > n2) a2 |= bit;
      if (n2 > n3) a3 |= bit;
      o0 = n0; o1 = n1; o2 = n2; o3 = n3;
      if ((t & 31) == 31) {
        int w = t >> 5;
        Dbits[4 * lane + 0][w] = a0; a0 = 0;
        Dbits[4 * lane + 1][w] = a1; a1 = 0;
        Dbits[4 * lane + 2][w] = a2; a2 = 0;
        Dbits[4 * lane + 3][w] = a3; a3 = 0;
      }
    };
    int t = 1;
    for (; t + 15 < ml; t += 16) {
      step(t + 0,  rh[0],  rl[0]);  step(t + 1,  rh[1],  rl[1]);
      step(t + 2,  rh[2],  rl[2]);  step(t + 3,  rh[3],  rl[3]);
      step(t + 4,  rh[4],  rl[4]);  step(t + 5,  rh[5],  rl[5]);
      step(t + 6,  rh[6],  rl[6]);  step(t + 7,  rh[7],  rl[7]);
      step(t + 8,  rh[8],  rl[8]);  step(t + 9,  rh[9],  rl[9]);
      step(t + 10, rh[10], rl[10]); step(t + 11, rh[11], rl[11]);
      step(t + 12, rh[12], rl[12]); step(t + 13, rh[13], rl[13]);
      step(t + 14, rh[14], rl[14]); step(t + 15, rh[15], rl[15]);
    }
    #pragma unroll
    for (int k = 0; k < 16; ++k) { if (t + k < ml) step(t + k, rh[k], rl[k]); }
    if (((ml - 1) & 31) != 31) {
      int w = (ml - 1) >> 5;
      Dbits[4 * lane + 0][w] = a0;
      Dbits[4 * lane + 1][w] = a1;
      Dbits[4 * lane + 2][w] = a2;
      Dbits[4 * lane + 3][w] = a3;
    }
    __builtin_amdgcn_s_waitcnt(0xC07F);  // drain LDS writes (single wave, lockstep)

    // -------- literal backtrack (validated R2 semantics) --------
    if (lane == 0) {
      int* pb = pathg + b * TLEN;
      int r = tl - 1;
      pb[ml - 1] = r;
      int curR = 1 << 30, curW = -1;
      uint32_t W = 0;
      for (int qq = ml - 2; qq >= 0; --qq) {
        int w = qq >> 5;
        if (r >= 0 && (r != curR || w != curW)) { W = Dbits[r][w]; curR = r; curW = w; }
        int g = (r >= 0) ? (int)((W >> (qq & 31)) & 1u) : 0;
        r -= g;
        pb[qq] = r;
      }
    }
  }
}

// ---------------------------------------------------------------------------
// K3: zero the alignment region (held lo-scratch until now).
// ---------------------------------------------------------------------------
__global__ __launch_bounds__(256) void zero_kernel(float* __restrict__ out) {
  size_t i = ((size_t)blockIdx.x * 256 + threadIdx.x) * 4;
  *(float4*)(out + OFF_ALIGN + i) = make_float4(0.f, 0.f, 0.f, 0.f);
}

// ---------------------------------------------------------------------------
// K4: scatter one-hot 1.0 entries.
// ---------------------------------------------------------------------------
__global__ __launch_bounds__(256) void ones_kernel(
    const int* __restrict__ mlen, const int* __restrict__ pathg, float* __restrict__ out) {
  int b = blockIdx.x;
  int ml = mlen[b];
  float* al = out + OFF_ALIGN;
  for (int t = threadIdx.x; t < ml; t += 256) {
    int p = pathg[b * TLEN + t];
    if (p >= 0) al[((size_t)b * TLEN + t) * LLEN + p] = 1.0f;
  }
}

extern "C" void kernel_launch(void* const* d_in, const int* in_sizes, int n_in,
                              void* d_out, int out_size, void* d_ws, size_t ws_size,
                              hipStream_t stream) {
  const float* mu_logvar = (const float*)d_in[0];
  const float* z         = (const float*)d_in[1];
  const int*   tlv       = (const int*)d_in[2];
  const int*   mlv       = (const int*)d_in[3];
  float* out = (float*)d_out;
  char*  wsb = (char*)d_ws;

  double* Ad   = (double*)(wsb + WSB_A);
  double* Kcd  = (double*)(wsb + WSB_KC);
  float*  lpTh = (float*)(wsb + WSB_LPT);
  int*    path = (int*)(wsb + WSB_PATH);

  prep_kernel<<<dim3(BB * LLEN / 4), 256, 0, stream>>>(mu_logvar, Ad, Kcd);
  lp_kernel<<<dim3(13, 8, BB), 128, 0, stream>>>(z, Ad, Kcd, out, lpTh);
  dp_kernel<<<dim3(2 * BB), 64, 0, stream>>>(lpTh, out, tlv, mlv, out, path);
  zero_kernel<<<dim3((BB * TLEN * LLEN) / (256 * 4)), 256, 0, stream>>>(out);
  ones_kernel<<<dim3(BB), 256, 0, stream>>>(mlv, path, out);
}